// Round 5
// baseline (144.615 us; speedup 1.0000x reference)
//
#include <hip/hip_runtime.h>

// Problem constants (fixed by reference)
#define BB 8
#define NN 128
#define CC 64
static constexpr float INV_A = 1.0f / 49.0f;   // average_nobj = 49.0

// Workspace layout (float offsets)
#define OFF_C    0           // C[b][d][s], 15*64*64 fp32 (for k_uv)
#define OFF_CB   61440       // Cb bf16 [s][k=128]: k<64 -> C3[d][s], k>=64 -> C4[d][s]
#define OFF_RS   65536       // rowsum/A  [n][i][d]
#define OFF_CS   131072      // colsum/A  [n][j][d]
#define OFF_DV   196608      // diag      [n][i][d]
#define OFF_U1   263168      // U1 + S + bias      [n][i][s]
#define OFF_U2   328704      // U2                 [n][j][s]
#define OFF_DG   394240      // diag term + dbias  [n][i][s]

typedef __attribute__((ext_vector_type(8))) short v8s;
typedef __attribute__((ext_vector_type(4))) float v4f;

// pack two fp32 -> one dword of two bf16 (round-half-up; err <= 2^-9 rel)
static __device__ inline unsigned pack2bf(float a, float b) {
    union { float f; unsigned u; } ua, ub; ua.f = a; ub.f = b;
    return ((ua.u + 0x8000u) >> 16) | ((ub.u + 0x8000u) & 0xffff0000u);
}
static __device__ inline unsigned short f2bf(float a) {
    union { float f; unsigned u; } ua; ua.f = a;
    return (unsigned short)((ua.u + 0x8000u) >> 16);
}

// ---------------------------------------------------------------------------
// K_pre: blocks [0,512): row/col sums + diagonal capture.
//        blocks [512,784): coefficient tables (fp32 C for k_uv, bf16 Cb).
__global__ void k_pre(const float* __restrict__ in,
                      const float* __restrict__ c00, const float* __restrict__ c01,
                      const float* __restrict__ c10, const float* __restrict__ c11,
                      float* __restrict__ ws) {
    if (blockIdx.x >= 512) {
        int idx = (blockIdx.x - 512) * 256 + threadIdx.x;
        if (idx < 15 * 4096) {
            int b = idx >> 12; int r = idx & 4095; int d = r >> 6; int s = r & 63;
            ws[OFF_C + idx] = c00[d * 15 + b] * c10[d * 64 + s] + c01[s * 15 + b] * c11[d * 64 + s];
        } else if (idx < 15 * 4096 + 8192) {
            int k = idx - 15 * 4096;
            int which = k >> 12;           // 0 -> b=3 (identity), 1 -> b=4 (transpose)
            int r = k & 4095; int s = r >> 6; int d = r & 63;
            int b = 3 + which;
            float v = c00[d * 15 + b] * c10[d * 64 + s] + c01[s * 15 + b] * c11[d * 64 + s];
            unsigned short* cb = (unsigned short*)(ws + OFF_CB);
            cb[s * 128 + which * 64 + d] = f2bf(v);
        }
        return;
    }
    __shared__ float4 part[4][4][16];
    int mode = blockIdx.x >> 8;            // 0 rowsum(+diag), 1 colsum
    int bb = blockIdx.x & 255;
    int n = bb >> 5; int g0 = (bb & 31) * 4;
    int t = threadIdx.x;
    int q = t >> 6; int ii = (t >> 4) & 3; int d4 = t & 15;
    float4 acc = make_float4(0.f, 0.f, 0.f, 0.f);
    if (mode == 0) {
        int i = g0 + ii;
        float4 dvv = acc; bool hd = false;
        const float* base = in + ((size_t)(n * NN + i)) * NN * CC + d4 * 4;
        for (int j = q * 32; j < q * 32 + 32; ++j) {
            float4 v = *(const float4*)(base + (size_t)j * CC);
            acc.x += v.x; acc.y += v.y; acc.z += v.z; acc.w += v.w;
            if (j == i) { dvv = v; hd = true; }
        }
        if (hd) *(float4*)(ws + OFF_DV + ((size_t)(n * NN + i)) * CC + d4 * 4) = dvv;
    } else {
        int j = g0 + ii;
        for (int i = q * 32; i < q * 32 + 32; ++i) {
            float4 v = *(const float4*)(in + (((size_t)(n * NN + i)) * NN + j) * CC + d4 * 4);
            acc.x += v.x; acc.y += v.y; acc.z += v.z; acc.w += v.w;
        }
    }
    part[q][ii][d4] = acc;
    __syncthreads();
    if (t < 64) {
        int i2 = t >> 4; int dd = t & 15;
        float4 a = part[0][i2][dd], b = part[1][i2][dd], c = part[2][i2][dd], d = part[3][i2][dd];
        float4 s;
        s.x = (a.x + b.x + c.x + d.x) * INV_A;
        s.y = (a.y + b.y + c.y + d.y) * INV_A;
        s.z = (a.z + b.z + c.z + d.z) * INV_A;
        s.w = (a.w + b.w + c.w + d.w) * INV_A;
        *(float4*)(ws + (mode ? OFF_CS : OFF_RS) + ((size_t)(n * NN + g0 + i2)) * CC + dd * 4) = s;
    }
}

// ---------------------------------------------------------------------------
// K_uv: broadcast-term GEMMs. 2-row blocks, grid 512. Phase-1 vectorized
// (float4 loads, 16/thread instead of 64 scalar).
__global__ __launch_bounds__(256, 4) void k_uv(const float* __restrict__ bias,
                                               const float* __restrict__ dbias,
                                               float* __restrict__ ws) {
    __shared__ float trL[64], asL[64];
    __shared__ float4 ptr4[16][17], pas4[16][17];
    __shared__ float pU1[4][2][64], pU2[4][2][64], pDG[4][2][64];
    __shared__ float pS[4][64], pDGc[4][64];
    int n = blockIdx.x >> 6; int i0 = (blockIdx.x & 63) * 2;
    int t = threadIdx.x;
    int s = t & 63; int q = t >> 6;

    {   // phase 1: trace/A and allsum/A^2 for this n (vectorized, L2-hot)
        int d4 = t & 15; int iq = t >> 4;     // 16 channel-quads x 16 i-groups of 8
        float4 tr4 = make_float4(0.f, 0.f, 0.f, 0.f);
        float4 as4 = tr4;
        #pragma unroll
        for (int e = 0; e < 8; ++e) {
            size_t ro = ((size_t)(n * NN + iq * 8 + e)) * CC + d4 * 4;
            float4 dv = *(const float4*)(ws + OFF_DV + ro);
            float4 rs = *(const float4*)(ws + OFF_RS + ro);
            tr4.x += dv.x; tr4.y += dv.y; tr4.z += dv.z; tr4.w += dv.w;
            as4.x += rs.x; as4.y += rs.y; as4.z += rs.z; as4.w += rs.w;
        }
        ptr4[iq][d4] = tr4; pas4[iq][d4] = as4;
        __syncthreads();
        if (t < 64) {
            int dd = t >> 2; int comp = t & 3;
            float tr = 0.f, as = 0.f;
            #pragma unroll
            for (int g = 0; g < 16; ++g) {
                const float* pt = (const float*)&ptr4[g][dd];
                const float* pa = (const float*)&pas4[g][dd];
                tr += pt[comp]; as += pa[comp];
            }
            trL[t] = tr * INV_A; asL[t] = as * INV_A;
        }
        __syncthreads();
    }

    const float* C = ws + OFF_C;
    float aU1[2] = {0, 0}, aU2[2] = {0, 0}, aDG[2] = {0, 0};
    float aS = 0.f, aDGc = 0.f;
    #pragma unroll
    for (int c4 = 0; c4 < 4; ++c4) {
        int dc = q * 4 + c4;
        float tr4[4], as4[4], dv4[2][4], rs4[2][4], cs4[2][4];
        #pragma unroll
        for (int k = 0; k < 4; ++k) { tr4[k] = trL[dc * 4 + k]; as4[k] = asL[dc * 4 + k]; }
        #pragma unroll
        for (int ii = 0; ii < 2; ++ii) {
            size_t ro = ((size_t)(n * NN + i0 + ii)) * CC + dc * 4;
            float4 v = *(const float4*)(ws + OFF_DV + ro);
            dv4[ii][0] = v.x; dv4[ii][1] = v.y; dv4[ii][2] = v.z; dv4[ii][3] = v.w;
            float4 r = *(const float4*)(ws + OFF_RS + ro);
            rs4[ii][0] = r.x; rs4[ii][1] = r.y; rs4[ii][2] = r.z; rs4[ii][3] = r.w;
            float4 c = *(const float4*)(ws + OFF_CS + ro);
            cs4[ii][0] = c.x; cs4[ii][1] = c.y; cs4[ii][2] = c.z; cs4[ii][3] = c.w;
        }
        #pragma unroll
        for (int k = 0; k < 4; ++k) {
            int d = dc * 4 + k;
            const float* Cd = C + d * 64 + s;
            float c0 = Cd[0 * 4096], c1 = Cd[1 * 4096], c2 = Cd[2 * 4096];
            float c5 = Cd[5 * 4096], c6 = Cd[6 * 4096], c7 = Cd[7 * 4096];
            float c8 = Cd[8 * 4096], c9 = Cd[9 * 4096], c10v = Cd[10 * 4096];
            float c11v = Cd[11 * 4096], c12v = Cd[12 * 4096];
            float c13 = Cd[13 * 4096], c14 = Cd[14 * 4096];
            aS += c13 * tr4[k] + c14 * as4[k];
            aDGc += c7 * tr4[k] + c8 * as4[k];
            #pragma unroll
            for (int ii = 0; ii < 2; ++ii) {
                aU1[ii] += c1 * dv4[ii][k] + c9 * rs4[ii][k] + c11v * cs4[ii][k];
                aU2[ii] += c2 * dv4[ii][k] + c10v * rs4[ii][k] + c12v * cs4[ii][k];
                aDG[ii] += c0 * dv4[ii][k] + c5 * rs4[ii][k] + c6 * cs4[ii][k];
            }
        }
    }
    #pragma unroll
    for (int ii = 0; ii < 2; ++ii) {
        pU1[q][ii][s] = aU1[ii]; pU2[q][ii][s] = aU2[ii]; pDG[q][ii][s] = aDG[ii];
    }
    pS[q][s] = aS; pDGc[q][s] = aDGc;
    __syncthreads();

    if (t < 128) {
        int fi = t >> 6; int s2 = t & 63;
        float u1 = pU1[0][fi][s2] + pU1[1][fi][s2] + pU1[2][fi][s2] + pU1[3][fi][s2];
        float u2 = pU2[0][fi][s2] + pU2[1][fi][s2] + pU2[2][fi][s2] + pU2[3][fi][s2];
        float dg = pDG[0][fi][s2] + pDG[1][fi][s2] + pDG[2][fi][s2] + pDG[3][fi][s2];
        float aSt = pS[0][s2] + pS[1][s2] + pS[2][s2] + pS[3][s2];
        float aDGct = pDGc[0][s2] + pDGc[1][s2] + pDGc[2][s2] + pDGc[3][s2];
        size_t row = ((size_t)(n * NN + i0 + fi)) * CC + s2;
        ws[OFF_U1 + row] = u1 + aSt + bias[s2];
        ws[OFF_U2 + row] = u2;
        ws[OFF_DG + row] = dg + aDGct + dbias[s2];
    }
}

// ---------------------------------------------------------------------------
// K_main: MFMA kernel, FULL-ROW blocks. Block = (n, i): 128 pixels x 64 s,
// K=128. A[p][k]: k<64 = x[n,i,p,:], k>=64 = x[n,p,i,:] (direct, L3-hot).
// B staged once per block (was twice). 32 MFMA/block. LDS 52 KB -> 3 blk/CU.
__global__ __launch_bounds__(256, 3) void k_main(
        const float* __restrict__ in, const float* __restrict__ mask,
        const float* __restrict__ ws, float* __restrict__ out) {
    __shared__ __align__(16) unsigned char smem[52224];
    unsigned short* Ab = (unsigned short*)smem;            // 128 x 136 bf16 (34816 B)
    unsigned short* Bb = (unsigned short*)(smem + 34816);  // 64 x 136 bf16 (17408 B)
    float* Obuf = (float*)smem;                            // 128 x 68 fp32, aliases Ab

    int blk = blockIdx.x;
    int n = blk >> 7; int i = blk & 127;
    int t = threadIdx.x;
    int tp = t >> 4; int c = t & 15;

    // ---- stage B: 64x128 bf16 from ws Cb (16 KB, L2-hot), once ----
    const unsigned short* cb = (const unsigned short*)(ws + OFF_CB);
    #pragma unroll
    for (int e = 0; e < 4; ++e) {
        int s = e * 16 + tp;
        float4 v = *(const float4*)(cb + s * 128 + c * 8);     // raw 16B copy
        *(float4*)((unsigned char*)(Bb + s * 136 + c * 8)) = v;
    }
    // ---- stage A row-half: x[n,i,0..128,:] fp32 -> bf16, coalesced ----
    {
        const float* src = in + ((size_t)(n * NN + i)) * NN * CC;
        #pragma unroll
        for (int e = 0; e < 8; ++e) {
            int p = e * 16 + tp;
            float4 v = *(const float4*)(src + (size_t)p * CC + c * 4);
            uint2 pk; pk.x = pack2bf(v.x, v.y); pk.y = pack2bf(v.z, v.w);
            *(uint2*)(Ab + p * 136 + c * 4) = pk;
        }
    }
    // ---- stage A col-half: x[n,p,i,:] fp32 direct (256B rows, L3-hot) ----
    {
        const float* srcT = in + ((size_t)(n * NN) * NN + i) * CC;
        #pragma unroll
        for (int r = 0; r < 8; ++r) {
            int idx = t + r * 256;
            int p = idx >> 4; int cq = idx & 15;
            float4 v = *(const float4*)(srcT + (size_t)p * NN * CC + cq * 4);
            uint2 pk; pk.x = pack2bf(v.x, v.y); pk.y = pack2bf(v.z, v.w);
            *(uint2*)(Ab + p * 136 + 64 + cq * 4) = pk;
        }
    }
    __syncthreads();

    // ---- MFMA compute: wave w owns A-rows [w*32, w*32+32) ----
    int w = t >> 6; int l = t & 63;
    int r16 = l & 15; int quad = l >> 4;
    v4f acc[2][4];
    #pragma unroll
    for (int h = 0; h < 2; ++h)
        #pragma unroll
        for (int st = 0; st < 4; ++st) acc[h][st] = 0.f;
    #pragma unroll
    for (int kk = 0; kk < 4; ++kk) {
        v8s af0 = *(const v8s*)(Ab + (w * 32 + r16) * 136 + kk * 32 + quad * 8);
        v8s af1 = *(const v8s*)(Ab + (w * 32 + 16 + r16) * 136 + kk * 32 + quad * 8);
        #pragma unroll
        for (int st = 0; st < 4; ++st) {
            v8s bfr = *(const v8s*)(Bb + (st * 16 + r16) * 136 + kk * 32 + quad * 8);
            acc[0][st] = __builtin_amdgcn_mfma_f32_16x16x32_bf16(af0, bfr, acc[0][st], 0, 0, 0);
            acc[1][st] = __builtin_amdgcn_mfma_f32_16x16x32_bf16(af1, bfr, acc[1][st], 0, 0, 0);
        }
    }
    // acc -> Obuf (wave w writes only rows [w*32, w*32+32), which only it read)
    #pragma unroll
    for (int h = 0; h < 2; ++h)
        #pragma unroll
        for (int st = 0; st < 4; ++st)
            #pragma unroll
            for (int reg = 0; reg < 4; ++reg)
                Obuf[(w * 32 + h * 16 + quad * 4 + reg) * 68 + st * 16 + r16] = acc[h][st][reg];
    __syncthreads();

    // ---- epilogue: +U1[i] +U2[j] +(i==j)DG, leaky relu, mask, f4 store ----
    int srow = (n * NN + i) * CC;
    float4 u1 = *(const float4*)(ws + OFF_U1 + srow + c * 4);
    float4 dg = *(const float4*)(ws + OFF_DG + srow + c * 4);
    #pragma unroll
    for (int e = 0; e < 8; ++e) {
        int j = e * 16 + tp;
        float4 v = *(const float4*)(Obuf + j * 68 + c * 4);
        float4 u2 = *(const float4*)(ws + OFF_U2 + (n * NN + j) * CC + c * 4);
        v.x += u1.x + u2.x; v.y += u1.y + u2.y; v.z += u1.z + u2.z; v.w += u1.w + u2.w;
        if (j == i) { v.x += dg.x; v.y += dg.y; v.z += dg.z; v.w += dg.w; }
        v.x = v.x > 0.f ? v.x : 0.01f * v.x;
        v.y = v.y > 0.f ? v.y : 0.01f * v.y;
        v.z = v.z > 0.f ? v.z : 0.01f * v.z;
        v.w = v.w > 0.f ? v.w : 0.01f * v.w;
        float m = mask[((size_t)(n * NN + i)) * NN + j];
        v.x *= m; v.y *= m; v.z *= m; v.w *= m;
        *(float4*)(out + (((size_t)(n * NN + i)) * NN + j) * CC + c * 4) = v;
    }
}

// ---------------------------------------------------------------------------
extern "C" void kernel_launch(void* const* d_in, const int* in_sizes, int n_in,
                              void* d_out, int out_size, void* d_ws, size_t ws_size,
                              hipStream_t stream) {
    const float* inputs = (const float*)d_in[0];
    const float* mask   = (const float*)d_in[1];
    // d_in[2] = nobj (unused by the reference computation)
    const float* c00 = (const float*)d_in[3];
    const float* c01 = (const float*)d_in[4];
    const float* c10 = (const float*)d_in[5];
    const float* c11 = (const float*)d_in[6];
    const float* bias  = (const float*)d_in[7];
    const float* dbias = (const float*)d_in[8];
    float* out = (float*)d_out;
    float* ws = (float*)d_ws;

    k_pre <<<784, 256, 0, stream>>>(inputs, c00, c01, c10, c11, ws);
    k_uv  <<<512, 256, 0, stream>>>(bias, dbias, ws);
    k_main<<<1024, 256, 0, stream>>>(inputs, mask, ws, out);
}

// Round 6
// 132.434 us; speedup vs baseline: 1.0920x; 1.0920x over previous
//
#include <hip/hip_runtime.h>

// Problem constants (fixed by reference)
#define BB 8
#define NN 128
#define CC 64
static constexpr float INV_A = 1.0f / 49.0f;   // average_nobj = 49.0

// Workspace layout (float offsets)
#define OFF_C    0           // C[b][d][s], 15*64*64 fp32 (for k_uv)
#define OFF_CB   61440       // Cb bf16 [s][k=128]: k<64 -> C3[d][s], k>=64 -> C4[d][s]
#define OFF_RS   65536       // rowsum/A  [n][i][d]
#define OFF_CS   131072      // colsum/A  [n][j][d]
#define OFF_DV   196608      // diag      [n][i][d]
#define OFF_U1   263168      // U1 + S + bias      [n][i][s]
#define OFF_U2   328704      // U2                 [n][j][s]
#define OFF_DG   394240      // diag term + dbias  [n][i][s]
#define OFF_XT   459776      // xbT bf16 [n][j][i][d] = x[n,i,j,d]  (8.4M bf16)

typedef __attribute__((ext_vector_type(8))) short v8s;
typedef __attribute__((ext_vector_type(4))) float v4f;

// pack two fp32 -> one dword of two bf16 (round-half-up; err <= 2^-9 rel)
static __device__ inline unsigned pack2bf(float a, float b) {
    union { float f; unsigned u; } ua, ub; ua.f = a; ub.f = b;
    return ((ua.u + 0x8000u) >> 16) | ((ub.u + 0x8000u) & 0xffff0000u);
}
static __device__ inline unsigned short f2bf(float a) {
    union { float f; unsigned u; } ua; ua.f = a;
    return (unsigned short)((ua.u + 0x8000u) >> 16);
}

// ---------------------------------------------------------------------------
// K_pre (occupancy-restructured): blocks [0,1024): mode 0, one (n,i) row each:
//   rowsum + diag capture. blocks [1024,2048): mode 1, one (n,j) column each:
//   colsum + xbT bf16 transposed emit. blocks [2048,2320): coefficient tables.
//   2048 working blocks = 8/CU = 32 waves/CU (was 2 blocks/CU = 25% occ).
__global__ void k_pre(const float* __restrict__ in,
                      const float* __restrict__ c00, const float* __restrict__ c01,
                      const float* __restrict__ c10, const float* __restrict__ c11,
                      float* __restrict__ ws) {
    int bb = blockIdx.x;
    int t = threadIdx.x;
    if (bb >= 2048) {
        int idx = (bb - 2048) * 256 + t;
        if (idx < 15 * 4096) {
            int b = idx >> 12; int r = idx & 4095; int d = r >> 6; int s = r & 63;
            ws[OFF_C + idx] = c00[d * 15 + b] * c10[d * 64 + s] + c01[s * 15 + b] * c11[d * 64 + s];
        } else if (idx < 15 * 4096 + 8192) {
            int k = idx - 15 * 4096;
            int which = k >> 12;           // 0 -> b=3 (identity), 1 -> b=4 (transpose)
            int r = k & 4095; int s = r >> 6; int d = r & 63;
            int b = 3 + which;
            float v = c00[d * 15 + b] * c10[d * 64 + s] + c01[s * 15 + b] * c11[d * 64 + s];
            unsigned short* cb = (unsigned short*)(ws + OFF_CB);
            cb[s * 128 + which * 64 + d] = f2bf(v);
        }
        return;
    }
    __shared__ float4 part[16][16];        // [group][d4]
    int mode = bb >> 10;                   // 0 rowsum(+diag), 1 colsum(+xbT)
    int r = bb & 1023;
    int n = r >> 7; int i = r & 127;       // row (mode0) or column (mode1)
    int d4 = t & 15; int g = t >> 4;       // 16 element-groups of 8

    float4 acc = make_float4(0.f, 0.f, 0.f, 0.f);
    if (mode == 0) {
        const float* base = in + ((size_t)(n * NN + i)) * NN * CC + d4 * 4;
        float4 dvv = acc; bool hd = false;
        #pragma unroll
        for (int e = 0; e < 8; ++e) {
            int j = g * 8 + e;
            float4 v = *(const float4*)(base + (size_t)j * CC);
            acc.x += v.x; acc.y += v.y; acc.z += v.z; acc.w += v.w;
            if (j == i) { dvv = v; hd = true; }
        }
        if (hd) *(float4*)(ws + OFF_DV + ((size_t)(n * NN + i)) * CC + d4 * 4) = dvv;
    } else {
        const float* base = in + ((size_t)(n * NN) * NN + i) * CC + d4 * 4;
        unsigned short* xT = (unsigned short*)(ws + OFF_XT)
                           + ((size_t)(n * NN + i)) * NN * CC + d4 * 4;
        #pragma unroll
        for (int e = 0; e < 8; ++e) {
            int ii2 = g * 8 + e;
            float4 v = *(const float4*)(base + (size_t)ii2 * NN * CC);
            acc.x += v.x; acc.y += v.y; acc.z += v.z; acc.w += v.w;
            uint2 pk; pk.x = pack2bf(v.x, v.y); pk.y = pack2bf(v.z, v.w);
            *(uint2*)(xT + (size_t)ii2 * CC) = pk;
        }
    }
    part[g][d4] = acc;
    __syncthreads();
    if (t < 64) {   // 16 d4 x 4 quarters: each sums 4 partials (slot qq*4 self-owned)
        int dd = t & 15; int qq = t >> 4;
        float4 a = part[qq * 4 + 0][dd], b = part[qq * 4 + 1][dd];
        float4 c = part[qq * 4 + 2][dd], d = part[qq * 4 + 3][dd];
        float4 s;
        s.x = a.x + b.x + c.x + d.x; s.y = a.y + b.y + c.y + d.y;
        s.z = a.z + b.z + c.z + d.z; s.w = a.w + b.w + c.w + d.w;
        part[qq * 4][dd] = s;
    }
    __syncthreads();
    if (t < 16) {
        float4 a = part[0][t], b = part[4][t], c = part[8][t], d = part[12][t];
        float4 s;
        s.x = (a.x + b.x + c.x + d.x) * INV_A;
        s.y = (a.y + b.y + c.y + d.y) * INV_A;
        s.z = (a.z + b.z + c.z + d.z) * INV_A;
        s.w = (a.w + b.w + c.w + d.w) * INV_A;
        *(float4*)(ws + (mode ? OFF_CS : OFF_RS) + ((size_t)(n * NN + i)) * CC + t * 4) = s;
    }
}

// ---------------------------------------------------------------------------
// K_uv: fused trace/allsum + broadcast-term GEMMs (exact R0-best version).
__global__ __launch_bounds__(256, 4) void k_uv(const float* __restrict__ bias,
                                               const float* __restrict__ dbias,
                                               float* __restrict__ ws) {
    __shared__ float trL[64], asL[64];
    __shared__ float pU1[4][4][64], pU2[4][4][64], pDG[4][4][64];
    __shared__ float pS[4][64], pDGc[4][64];
    int n = blockIdx.x >> 5; int i0 = (blockIdx.x & 31) * 4;
    int t = threadIdx.x;
    int s = t & 63; int q = t >> 6;

    {
        float tr = 0.f, as = 0.f;
        #pragma unroll 4
        for (int e = 0; e < 32; ++e) {
            int i = q * 32 + e;
            tr += ws[OFF_DV + ((size_t)(n * NN + i)) * CC + s];
            as += ws[OFF_RS + ((size_t)(n * NN + i)) * CC + s];
        }
        pS[q][s] = tr; pDGc[q][s] = as;
        __syncthreads();
        if (t < 64) {
            trL[t] = (pS[0][t] + pS[1][t] + pS[2][t] + pS[3][t]) * INV_A;
            asL[t] = (pDGc[0][t] + pDGc[1][t] + pDGc[2][t] + pDGc[3][t]) * INV_A;
        }
        __syncthreads();
    }

    const float* C = ws + OFF_C;
    float aU1[4] = {0, 0, 0, 0}, aU2[4] = {0, 0, 0, 0}, aDG[4] = {0, 0, 0, 0};
    float aS = 0.f, aDGc = 0.f;
    #pragma unroll
    for (int c4 = 0; c4 < 4; ++c4) {
        int dc = q * 4 + c4;
        float tr4[4], as4[4], dv4[4][4], rs4[4][4], cs4[4][4];
        #pragma unroll
        for (int k = 0; k < 4; ++k) { tr4[k] = trL[dc * 4 + k]; as4[k] = asL[dc * 4 + k]; }
        #pragma unroll
        for (int ii = 0; ii < 4; ++ii) {
            size_t ro = ((size_t)(n * NN + i0 + ii)) * CC + dc * 4;
            float4 v = *(const float4*)(ws + OFF_DV + ro);
            dv4[ii][0] = v.x; dv4[ii][1] = v.y; dv4[ii][2] = v.z; dv4[ii][3] = v.w;
            float4 r = *(const float4*)(ws + OFF_RS + ro);
            rs4[ii][0] = r.x; rs4[ii][1] = r.y; rs4[ii][2] = r.z; rs4[ii][3] = r.w;
            float4 c = *(const float4*)(ws + OFF_CS + ro);
            cs4[ii][0] = c.x; cs4[ii][1] = c.y; cs4[ii][2] = c.z; cs4[ii][3] = c.w;
        }
        #pragma unroll
        for (int k = 0; k < 4; ++k) {
            int d = dc * 4 + k;
            const float* Cd = C + d * 64 + s;
            float c0 = Cd[0 * 4096], c1 = Cd[1 * 4096], c2 = Cd[2 * 4096];
            float c5 = Cd[5 * 4096], c6 = Cd[6 * 4096], c7 = Cd[7 * 4096];
            float c8 = Cd[8 * 4096], c9 = Cd[9 * 4096], c10v = Cd[10 * 4096];
            float c11v = Cd[11 * 4096], c12v = Cd[12 * 4096];
            float c13 = Cd[13 * 4096], c14 = Cd[14 * 4096];
            aS += c13 * tr4[k] + c14 * as4[k];
            aDGc += c7 * tr4[k] + c8 * as4[k];
            #pragma unroll
            for (int ii = 0; ii < 4; ++ii) {
                aU1[ii] += c1 * dv4[ii][k] + c9 * rs4[ii][k] + c11v * cs4[ii][k];
                aU2[ii] += c2 * dv4[ii][k] + c10v * rs4[ii][k] + c12v * cs4[ii][k];
                aDG[ii] += c0 * dv4[ii][k] + c5 * rs4[ii][k] + c6 * cs4[ii][k];
            }
        }
    }
    #pragma unroll
    for (int ii = 0; ii < 4; ++ii) {
        pU1[q][ii][s] = aU1[ii]; pU2[q][ii][s] = aU2[ii]; pDG[q][ii][s] = aDG[ii];
    }
    pS[q][s] = aS; pDGc[q][s] = aDGc;
    __syncthreads();

    int fi = q;
    float u1 = pU1[0][fi][s] + pU1[1][fi][s] + pU1[2][fi][s] + pU1[3][fi][s];
    float u2 = pU2[0][fi][s] + pU2[1][fi][s] + pU2[2][fi][s] + pU2[3][fi][s];
    float dg = pDG[0][fi][s] + pDG[1][fi][s] + pDG[2][fi][s] + pDG[3][fi][s];
    float aSt = pS[0][s] + pS[1][s] + pS[2][s] + pS[3][s];
    float aDGct = pDGc[0][s] + pDGc[1][s] + pDGc[2][s] + pDGc[3][s];
    size_t row = ((size_t)(n * NN + i0 + fi)) * CC + s;
    ws[OFF_U1 + row] = u1 + aSt + bias[s];
    ws[OFF_U2 + row] = u2;
    ws[OFF_DG + row] = dg + aDGct + dbias[s];
}

// ---------------------------------------------------------------------------
// K_main: MFMA kernel (exact R0-best version). Block = (n, i, j-half):
// 64 pixels x 64 s, K=128. A k<64 = x rows (fp32->bf16), k>=64 = xbT (bf16,
// contiguous coalesced). 34 KB LDS, 4 blocks/CU.
__global__ __launch_bounds__(256, 4) void k_main(
        const float* __restrict__ in, const float* __restrict__ mask,
        const float* __restrict__ ws, float* __restrict__ out) {
    __shared__ __align__(16) unsigned char smem[34816];
    unsigned short* Ab = (unsigned short*)smem;            // 64 x 136 bf16
    unsigned short* Bb = (unsigned short*)(smem + 17408);  // 64 x 136 bf16
    float* Obuf = (float*)smem;                            // 64 x 68 fp32, aliases Ab

    int blk = blockIdx.x;
    int n = blk >> 8; int rem = blk & 255; int i = rem >> 1; int j0 = (rem & 1) * 64;
    int t = threadIdx.x;
    int tp = t >> 4; int c = t & 15;

    // ---- stage B: 64x128 bf16 from ws Cb (16 KB, L2-hot) ----
    const unsigned short* cb = (const unsigned short*)(ws + OFF_CB);
    #pragma unroll
    for (int e = 0; e < 4; ++e) {
        int s = e * 16 + tp;
        float4 v = *(const float4*)(cb + s * 128 + c * 8);     // raw 16B copy
        *(float4*)((unsigned char*)(Bb + s * 136 + c * 8)) = v;
    }
    // ---- stage A row-half: x[n,i,j0..j0+64,:] fp32 -> bf16 ----
    {
        const float* src = in + (((size_t)(n * NN + i)) * NN + j0) * CC;
        #pragma unroll
        for (int e = 0; e < 4; ++e) {
            int p = e * 16 + tp;
            float4 v = *(const float4*)(src + (size_t)p * CC + c * 4);
            uint2 pk; pk.x = pack2bf(v.x, v.y); pk.y = pack2bf(v.z, v.w);
            *(uint2*)(Ab + p * 136 + c * 4) = pk;
        }
    }
    // ---- stage A col-half: xbT[n][i][j0+p][:] bf16, fully coalesced 16B/lane ----
    {
        const unsigned short* xT = (const unsigned short*)(ws + OFF_XT)
                                 + (((size_t)(n * NN + i)) * NN + j0) * CC;
        #pragma unroll
        for (int r = 0; r < 2; ++r) {
            int idx = t + r * 256;
            int p = idx >> 3; int ch = idx & 7;
            float4 v = *(const float4*)(xT + (size_t)p * CC + ch * 8);  // 8 bf16
            *(float4*)((unsigned char*)(Ab + p * 136 + 64 + ch * 8)) = v;
        }
    }
    __syncthreads();

    // ---- MFMA compute ----
    int w = t >> 6; int l = t & 63;
    int r16 = l & 15; int quad = l >> 4;
    v4f acc[4];
    #pragma unroll
    for (int st = 0; st < 4; ++st) acc[st] = 0.f;
    int arow = w * 16 + r16;
    #pragma unroll
    for (int kk = 0; kk < 4; ++kk) {
        v8s af = *(const v8s*)(Ab + arow * 136 + kk * 32 + quad * 8);
        #pragma unroll
        for (int st = 0; st < 4; ++st) {
            v8s bfr = *(const v8s*)(Bb + (st * 16 + r16) * 136 + kk * 32 + quad * 8);
            acc[st] = __builtin_amdgcn_mfma_f32_16x16x32_bf16(af, bfr, acc[st], 0, 0, 0);
        }
    }
    // acc -> Obuf (wave w writes only rows [w*16, w*16+16), which only it read)
    #pragma unroll
    for (int st = 0; st < 4; ++st)
        #pragma unroll
        for (int reg = 0; reg < 4; ++reg)
            Obuf[(w * 16 + quad * 4 + reg) * 68 + st * 16 + r16] = acc[st][reg];
    __syncthreads();

    // ---- epilogue: +U1[i] +U2[j] +(i==j)DG, leaky relu, mask, f4 store ----
    int srow = (n * NN + i) * CC;
    float4 u1 = *(const float4*)(ws + OFF_U1 + srow + c * 4);
    float4 dg = *(const float4*)(ws + OFF_DG + srow + c * 4);
    #pragma unroll
    for (int e = 0; e < 4; ++e) {
        int p = e * 16 + tp;
        int j = j0 + p;
        float4 v = *(const float4*)(Obuf + p * 68 + c * 4);
        float4 u2 = *(const float4*)(ws + OFF_U2 + (n * NN + j) * CC + c * 4);
        v.x += u1.x + u2.x; v.y += u1.y + u2.y; v.z += u1.z + u2.z; v.w += u1.w + u2.w;
        if (j == i) { v.x += dg.x; v.y += dg.y; v.z += dg.z; v.w += dg.w; }
        v.x = v.x > 0.f ? v.x : 0.01f * v.x;
        v.y = v.y > 0.f ? v.y : 0.01f * v.y;
        v.z = v.z > 0.f ? v.z : 0.01f * v.z;
        v.w = v.w > 0.f ? v.w : 0.01f * v.w;
        float m = mask[((size_t)(n * NN + i)) * NN + j];
        v.x *= m; v.y *= m; v.z *= m; v.w *= m;
        *(float4*)(out + (((size_t)(n * NN + i)) * NN + j) * CC + c * 4) = v;
    }
}

// ---------------------------------------------------------------------------
extern "C" void kernel_launch(void* const* d_in, const int* in_sizes, int n_in,
                              void* d_out, int out_size, void* d_ws, size_t ws_size,
                              hipStream_t stream) {
    const float* inputs = (const float*)d_in[0];
    const float* mask   = (const float*)d_in[1];
    // d_in[2] = nobj (unused by the reference computation)
    const float* c00 = (const float*)d_in[3];
    const float* c01 = (const float*)d_in[4];
    const float* c10 = (const float*)d_in[5];
    const float* c11 = (const float*)d_in[6];
    const float* bias  = (const float*)d_in[7];
    const float* dbias = (const float*)d_in[8];
    float* out = (float*)d_out;
    float* ws = (float*)d_ws;

    k_pre <<<2320, 256, 0, stream>>>(inputs, c00, c01, c10, c11, ws);
    k_uv  <<<256,  256, 0, stream>>>(bias, dbias, ws);
    k_main<<<2048, 256, 0, stream>>>(inputs, mask, ws, out);
}